// Round 17
// baseline (284.734 us; speedup 1.0000x reference)
//
#include <hip/hip_runtime.h>

typedef unsigned short u16;
typedef __attribute__((ext_vector_type(8))) short bf16x8;
typedef __attribute__((ext_vector_type(4))) float f32x4;
typedef __attribute__((ext_vector_type(4))) unsigned short u16x4;

__device__ __forceinline__ u16 f2bf(float f) {
  union { float f; unsigned u; } v; v.f = f;
  return (u16)((v.u + 0x7FFFu + ((v.u >> 16) & 1u)) >> 16);
}

__device__ __forceinline__ void gload16(const u16* g, u16* l) {
  __builtin_amdgcn_global_load_lds((const __attribute__((address_space(1))) void*)g,
                                   (__attribute__((address_space(3))) void*)l, 16, 0, 0);
}

// ---------------- fp32 -> bf16 convert (5 tensors fused) ----------------
__global__ __launch_bounds__(256) void k_f2bf5(
    const float* __restrict__ i0, const float* __restrict__ i1, const float* __restrict__ i2,
    const float* __restrict__ i3, const float* __restrict__ i4,
    u16* o0, u16* o1, u16* o2, u16* o3, u16* o4, int n4x, int n4w) {
  const int seg = blockIdx.y;
  const float* in = (seg == 0) ? i0 : (seg == 1) ? i1 : (seg == 2) ? i2 : (seg == 3) ? i3 : i4;
  u16* out = (seg == 0) ? o0 : (seg == 1) ? o1 : (seg == 2) ? o2 : (seg == 3) ? o3 : o4;
  const int n4 = (seg == 0) ? n4x : n4w;
  int i = blockIdx.x * 256 + threadIdx.x;
  const int stride = gridDim.x * 256;
  for (; i < n4; i += stride) {
    const float4 v = ((const float4*)in)[i];
    u16x4 o;
    o.x = f2bf(v.x); o.y = f2bf(v.y); o.z = f2bf(v.z); o.w = f2bf(v.w);
    ((u16x4*)out)[i] = o;
  }
}

// ---------------- 128x128 GEMM, m97-structure + T2 swizzle + multi-block TLP ----------
template <int OUT_F32>
__global__ __launch_bounds__(256, 4) void k_gemm12(
    const u16* __restrict__ A, const u16* __restrict__ Bt,
    const float* __restrict__ b0, const float* __restrict__ b1, const float* __restrict__ b2,
    u16* __restrict__ C0, u16* __restrict__ C1, u16* __restrict__ C2,
    float* __restrict__ Cf, int NBM)
{
  __shared__ alignas(16) u16 As[8192];   // [128 rows][64 k], swizzled
  __shared__ alignas(16) u16 Bs[8192];

  const int tid = threadIdx.x;
  const int lane = tid & 63, wid = tid >> 6;
  const int fr = lane & 15, fg = lane >> 4;
  const int wr = wid >> 1, wc = wid & 1;

  const int nblk = gridDim.x;
  const int q = nblk >> 3, r = nblk & 7;
  const int xcd = blockIdx.x & 7, lid = blockIdx.x >> 3;
  const int wgid = (xcd < r ? xcd * (q + 1) : r * (q + 1) + (xcd - r) * q) + lid;
  const int mb = wgid % NBM, nb = wgid / NBM;
  const long row0 = (long)mb * 128;
  const long col0 = (long)nb * 128;

  int sRow[4], sCol[4];
#pragma unroll
  for (int i = 0; i < 4; ++i) {
    const int g = (wid * 4 + i) * 64 + lane;
    sRow[i] = g >> 3;
    sCol[i] = ((g & 7) ^ (sRow[i] & 7)) << 3;
  }

  const int sw = fr & 7;
  const int aBase = (wr * 64 + fr) * 64;
  const int bBase = (wc * 64 + fr) * 64;
  const int pc0 = (fg ^ sw) << 3;
  const int pc1 = ((4 + fg) ^ sw) << 3;

  f32x4 acc[4][4] = {};

#pragma unroll 1
  for (int t = 0; t < 32; ++t) {
    if (t) __syncthreads();
    const long k0 = (long)t << 6;
#pragma unroll
    for (int i = 0; i < 4; ++i) {
      gload16(A  + (row0 + sRow[i]) * 2048L + k0 + sCol[i], &As[(wid * 4 + i) * 512]);
      gload16(Bt + (col0 + sRow[i]) * 2048L + k0 + sCol[i], &Bs[(wid * 4 + i) * 512]);
    }
    __syncthreads();

#pragma unroll
    for (int kc = 0; kc < 2; ++kc) {
      const int pc = kc ? pc1 : pc0;
      bf16x8 a[4], b[4];
#pragma unroll
      for (int i = 0; i < 4; ++i) {
        a[i] = *(const bf16x8*)&As[aBase + i * 1024 + pc];
        b[i] = *(const bf16x8*)&Bs[bBase + i * 1024 + pc];
      }
#pragma unroll
      for (int i = 0; i < 4; ++i)
#pragma unroll
        for (int j = 0; j < 4; ++j)
          acc[i][j] = __builtin_amdgcn_mfma_f32_16x16x32_bf16(a[i], b[j], acc[i][j], 0, 0, 0);
    }
  }

  const int seg = (int)(col0 >> 11);
  const long colL = col0 & 2047;
  const float* bp = (seg == 0) ? b0 : (seg == 1) ? b1 : b2;
  u16* Cb = (seg == 0) ? C0 : (seg == 1) ? C1 : C2;
#pragma unroll
  for (int j = 0; j < 4; ++j) {
    const long cN = colL + wc * 64 + j * 16 + fr;
    const float bv = bp[cN];
#pragma unroll
    for (int i = 0; i < 4; ++i) {
      const long rM = row0 + wr * 64 + i * 16 + fg * 4;
#pragma unroll
      for (int reg = 0; reg < 4; ++reg) {
        const float v = acc[i][j][reg] + bv;
        if (OUT_F32) Cf[(rM + reg) * 2048 + cN] = v;
        else         Cb[(rM + reg) * 2048 + cN] = f2bf(v);
      }
    }
  }
}

// ---------------- V transpose: V[b][s][h*128+d] -> Vt[(b*16+h)*128+d][s] ----------------
__global__ __launch_bounds__(256) void k_transpose_v(const u16* __restrict__ V,
                                                     u16* __restrict__ Vt) {
  __shared__ u16 t[64][68];
  const int bh = blockIdx.z;
  const long s0 = (long)blockIdx.x * 64;
  const long d0 = (long)blockIdx.y * 64;
  const int tid = threadIdx.x;
  const long rowbase = (long)(bh >> 4) * 2048;
  const int hcol = (bh & 15) * 128;
#pragma unroll
  for (int i = 0; i < 4; ++i) {
    const int v = tid + i * 256;
    const int r = v >> 4, c4 = (v & 15) << 2;
    const u16x4 val = *(const u16x4*)&V[(rowbase + s0 + r) * 2048 + hcol + d0 + c4];
    *(u16x4*)&t[r][c4] = val;
  }
  __syncthreads();
#pragma unroll
  for (int i = 0; i < 4; ++i) {
    const int v = tid + i * 256;
    const int dr = v >> 4, s4 = (v & 15) << 2;
    u16x4 o;
    o.x = t[s4 + 0][dr]; o.y = t[s4 + 1][dr]; o.z = t[s4 + 2][dr]; o.w = t[s4 + 3][dr];
    *(u16x4*)&Vt[((long)bh * 128 + d0 + dr) * 2048 + s0 + s4] = o;
  }
}

// ---------------- causal flash attention v5: kv-split + single-buffer + 3-res TLP ----
// Grid 1024 = 32 qblk x 32 bh; ONE qblk per block, big-first dispatch
// (qblk = 31 - (L>>5)) so the dynamic scheduler backfills short blocks -> packed.
// XCD map: blocks of one bh share L&7 -> same XCD (K/V L2-resident).
// 256 thr = 4 waves (kvh = wid>>1, qh = wid&1): wave computes its 32-kv slice x
// 32 q-rows (kf/vf LDS traffic halved; each read feeds 2 MFMAs). Single-buffered
// K/V (32 KB) + P (10 KB) ~= 43 KB -> 3 blocks/CU; the per-step stage drain
// (__syncthreads) is covered by the other 2 resident blocks (m97/R9 mechanism).
// Per-wave online softmax over its kv-half; one cross-wave merge at the end
// (stats + O-scratch overlaid on the then-dead K/V/P region, syncthreads-fenced).
// Swapped operands (lane owns q-row fr) as proven in R13/R14.
__global__ __launch_bounds__(256, 3) void k_flash_attn(
    const u16* __restrict__ Q, const u16* __restrict__ K, const u16* __restrict__ Vt,
    u16* __restrict__ O)
{
  // SMEM carve (u16 units): [0,8192) Kt; [8192,16384) Vtt; [16384,21504) P [4][32][40];
  // [21504,22016) stats (2x128 f32). Merge scratch f32[2][32][132] = 16896 u16
  // overlays [0,16896) (K/V/P dead by then).
  __shared__ alignas(16) u16 SM[22016];
  u16* Kt  = SM;
  u16* Vtt = SM + 8192;
  u16* Pl  = SM + 16384;
  float* statsM = (float*)(SM + 21504);
  float* statsL = (float*)(SM + 21760);
  float* mergeO = (float*)SM;

  const int tid = threadIdx.x;
  const int lane = tid & 63, wid = tid >> 6;
  const int fr = lane & 15, fg = lane >> 4;
  const int kvh = wid >> 1, qh = wid & 1;

  const int L = blockIdx.x;
  const int bh = (L & 7) * 4 + ((L >> 3) & 3);
  const int qblk = 31 - (L >> 5);                // big blocks dispatch first

  const long rowbase = (long)(bh >> 4) * 2048;
  const int hcol = (bh & 15) * 128;
  const u16* Kg = K + rowbase * 2048 + hcol;
  const u16* Vg = Vt + (long)bh * 128 * 2048;
  const float scale2 = 0.08838834764831845f * 1.44269504089f;  // 1/sqrt(128)*log2(e)

  // staging: 8 x gload16 per thread per tile (K 16 chunks/row, V 8 chunks/row)
  int kR[4], kC[4], vR[4], vC[4];
#pragma unroll
  for (int i = 0; i < 4; ++i) {
    const int g = (wid * 4 + i) * 64 + lane;
    kR[i] = g >> 4;
    kC[i] = ((g & 15) ^ (kR[i] & 7)) << 3;
    vR[i] = g >> 3;
    vC[i] = ((g & 7) ^ (vR[i] & 7)) << 3;
  }

  const int sw = fr & 7;
  int kOff[2][4];
#pragma unroll
  for (int kvt = 0; kvt < 2; ++kvt)
#pragma unroll
    for (int c = 0; c < 4; ++c)
      kOff[kvt][c] = kvh * 4096 + kvt * 2048 + fr * 128 + (((c * 4 + fg) ^ sw) << 3);
  const int vB = fr * 64 + (((kvh * 4 + fg) ^ sw) << 3);
  const int pBase = wid * 1280;                  // P [32][40] per wave

  const int n = qblk + 1;
  const int qw = qblk * 64 + qh * 32;            // wave's first q row

  bf16x8 qf[2][4];
#pragma unroll
  for (int qs = 0; qs < 2; ++qs)
#pragma unroll
    for (int c = 0; c < 4; ++c)
      qf[qs][c] = *(const bf16x8*)&Q[(rowbase + qw + qs * 16 + fr) * 2048 + hcol + c * 32 + fg * 8];

  f32x4 oacc[2][8] = {};
  float m_run[2] = {-1e30f, -1e30f}, l_run[2] = {0.0f, 0.0f};

  for (int j = 0; j < n; ++j) {
    if (j) __syncthreads();                      // readers of previous tile done
    const long kv = (long)j * 64;
#pragma unroll
    for (int i = 0; i < 4; ++i) {
      gload16(Kg + (kv + kR[i]) * 2048 + kC[i], &Kt[(wid * 4 + i) * 512]);
      gload16(Vg + (long)vR[i] * 2048 + kv + vC[i], &Vtt[(wid * 4 + i) * 512]);
    }
    __syncthreads();                             // drain covered by other resident blocks

    const int kvbase = j * 64 + kvh * 32;        // wave's kv-slice start
    const bool skip = (kvbase >= qw + 32);
    if (!skip) {
      const bool needmask = (kvbase + 31 > qw);

      // ---- QK^T swapped: st[qs][kvt] = K-slice x Q -> D[kv local][q = fr] ----
      f32x4 st[2][2] = {};
      __builtin_amdgcn_s_setprio(1);
#pragma unroll
      for (int kvt = 0; kvt < 2; ++kvt)
#pragma unroll
        for (int c = 0; c < 4; ++c) {
          const bf16x8 kf = *(const bf16x8*)&Kt[kOff[kvt][c]];
          st[0][kvt] = __builtin_amdgcn_mfma_f32_16x16x32_bf16(kf, qf[0][c], st[0][kvt], 0, 0, 0);
          st[1][kvt] = __builtin_amdgcn_mfma_f32_16x16x32_bf16(kf, qf[1][c], st[1][kvt], 0, 0, 0);
        }
      __builtin_amdgcn_s_setprio(0);

      // ---- scale/mask + slice max (q lane-local) ----
      float pmax[2] = {-1e30f, -1e30f};
      if (needmask) {
#pragma unroll
        for (int qs = 0; qs < 2; ++qs) {
          const int qg = qw + qs * 16 + fr;
#pragma unroll
          for (int kvt = 0; kvt < 2; ++kvt)
#pragma unroll
            for (int r = 0; r < 4; ++r) {
              const int kg = kvbase + kvt * 16 + fg * 4 + r;
              const float v = (kg <= qg) ? st[qs][kvt][r] * scale2 : -1e30f;
              st[qs][kvt][r] = v;
              pmax[qs] = fmaxf(pmax[qs], v);
            }
        }
      } else {
#pragma unroll
        for (int qs = 0; qs < 2; ++qs)
#pragma unroll
          for (int kvt = 0; kvt < 2; ++kvt)
#pragma unroll
            for (int r = 0; r < 4; ++r) {
              const float v = st[qs][kvt][r] * scale2;
              st[qs][kvt][r] = v;
              pmax[qs] = fmaxf(pmax[qs], v);
            }
      }
#pragma unroll
      for (int qs = 0; qs < 2; ++qs) {
        pmax[qs] = fmaxf(pmax[qs], __shfl_xor(pmax[qs], 16));
        pmax[qs] = fmaxf(pmax[qs], __shfl_xor(pmax[qs], 32));
      }

      // ---- defer-max rescale (THR=8 log2 units) ----
      const int ok = (pmax[0] <= m_run[0] + 8.f) & (pmax[1] <= m_run[1] + 8.f);
      if (!__all(ok)) {
#pragma unroll
        for (int qs = 0; qs < 2; ++qs) {
          const float nm = fmaxf(m_run[qs], pmax[qs]);
          const float al = exp2f(m_run[qs] - nm);
          l_run[qs] *= al;
          m_run[qs] = nm;
#pragma unroll
          for (int dt = 0; dt < 8; ++dt)
#pragma unroll
            for (int r = 0; r < 4; ++r) oacc[qs][dt][r] *= al;
        }
      }

      // ---- P = exp2(s-m), slice sum ----
      float lsum[2] = {0.f, 0.f};
#pragma unroll
      for (int qs = 0; qs < 2; ++qs)
#pragma unroll
        for (int kvt = 0; kvt < 2; ++kvt)
#pragma unroll
          for (int r = 0; r < 4; ++r) {
            const float p = exp2f(st[qs][kvt][r] - m_run[qs]);
            st[qs][kvt][r] = p;
            lsum[qs] += p;
          }
#pragma unroll
      for (int qs = 0; qs < 2; ++qs) {
        lsum[qs] += __shfl_xor(lsum[qs], 16);
        lsum[qs] += __shfl_xor(lsum[qs], 32);
        l_run[qs] += lsum[qs];
      }

      // ---- P -> wave-private LDS: Pl[q 0..31][kv-local 0..31] ----
#pragma unroll
      for (int qs = 0; qs < 2; ++qs)
#pragma unroll
        for (int kvt = 0; kvt < 2; ++kvt)
#pragma unroll
          for (int r = 0; r < 4; ++r)
            Pl[pBase + (qs * 16 + fr) * 40 + kvt * 16 + fg * 4 + r] = f2bf(st[qs][kvt][r]);
      asm volatile("s_waitcnt lgkmcnt(0)" ::: "memory");
      __builtin_amdgcn_sched_barrier(0);

      // ---- O_partial += V-slice^T x P: each vf feeds 2 MFMAs ----
      const bf16x8 pf0 = *(const bf16x8*)&Pl[pBase + fr * 40 + fg * 8];
      const bf16x8 pf1 = *(const bf16x8*)&Pl[pBase + (16 + fr) * 40 + fg * 8];
      __builtin_amdgcn_s_setprio(1);
#pragma unroll
      for (int dt = 0; dt < 8; ++dt) {
        const bf16x8 vf = *(const bf16x8*)&Vtt[vB + dt * 1024];
        oacc[0][dt] = __builtin_amdgcn_mfma_f32_16x16x32_bf16(vf, pf0, oacc[0][dt], 0, 0, 0);
        oacc[1][dt] = __builtin_amdgcn_mfma_f32_16x16x32_bf16(vf, pf1, oacc[1][dt], 0, 0, 0);
      }
      __builtin_amdgcn_s_setprio(0);
    }
  }

  // ---- kv-half merge: partner = wid ^ 2; scratch overlays dead K/V/P ----
  __syncthreads();                               // all waves done with K/V/P
  if (fg == 0) {
#pragma unroll
    for (int qs = 0; qs < 2; ++qs) {
      statsM[wid * 32 + qs * 16 + fr] = m_run[qs];
      statsL[wid * 32 + qs * 16 + fr] = l_run[qs];
    }
  }
  __syncthreads();
  const int pw = wid ^ 2;
  float aself[2], ltot[2];
#pragma unroll
  for (int qs = 0; qs < 2; ++qs) {
    const float mp = statsM[pw * 32 + qs * 16 + fr];
    const float lp = statsL[pw * 32 + qs * 16 + fr];
    const float m = fmaxf(m_run[qs], mp);
    aself[qs] = exp2f(m_run[qs] - m);
    const float ap = exp2f(mp - m);
    ltot[qs] = aself[qs] * l_run[qs] + ap * lp;
  }
  if (kvh == 1) {
#pragma unroll
    for (int qs = 0; qs < 2; ++qs)
#pragma unroll
      for (int dt = 0; dt < 8; ++dt)
#pragma unroll
        for (int r = 0; r < 4; ++r)
          mergeO[qh * 4224 + (qs * 16 + fr) * 132 + dt * 16 + fg * 4 + r] =
              aself[qs] * oacc[qs][dt][r];
  }
  __syncthreads();
  if (kvh == 0) {
#pragma unroll
    for (int qs = 0; qs < 2; ++qs) {
      const float inv = 1.0f / ltot[qs];
      const long orow = (rowbase + qw + qs * 16 + fr) * 2048 + hcol;
#pragma unroll
      for (int dt = 0; dt < 8; ++dt) {
        u16x4 o;
#pragma unroll
        for (int r = 0; r < 4; ++r)
          o[r] = f2bf((aself[qs] * oacc[qs][dt][r] +
                       mergeO[qh * 4224 + (qs * 16 + fr) * 132 + dt * 16 + fg * 4 + r]) * inv);
        *(u16x4*)&O[orow + dt * 16 + fg * 4] = o;
      }
    }
  }
}

extern "C" void kernel_launch(void* const* d_in, const int* in_sizes, int n_in,
                              void* d_out, int out_size, void* d_ws, size_t ws_size,
                              hipStream_t stream) {
  const float* x  = (const float*)d_in[0];
  const float* Wq = (const float*)d_in[1];
  const float* bq = (const float*)d_in[2];
  const float* Wk = (const float*)d_in[3];
  const float* bk = (const float*)d_in[4];
  const float* Wv = (const float*)d_in[5];
  const float* bv = (const float*)d_in[6];
  const float* Wo = (const float*)d_in[7];
  const float* bo = (const float*)d_in[8];
  float* out = (float*)d_out;

  char* ws = (char*)d_ws;
  const size_t SZ_X = 16777216;   // 8M bf16
  const size_t SZ_W = 8388608;    // 4M bf16
  u16* xb  = (u16*)(ws);
  u16* wqb = (u16*)(ws + SZ_X);                 // wq/wk/wv contiguous = [6144][2048]
  u16* wkb = (u16*)(ws + SZ_X + 1 * SZ_W);
  u16* wvb = (u16*)(ws + SZ_X + 2 * SZ_W);
  u16* wob = (u16*)(ws + SZ_X + 3 * SZ_W);
  u16* Qb  = (u16*)(ws + 1 * SZ_X + 4 * SZ_W);
  u16* Kb  = (u16*)(ws + 2 * SZ_X + 4 * SZ_W);
  u16* Vb  = (u16*)(ws + 3 * SZ_X + 4 * SZ_W);
  u16* Vtb = (u16*)(ws + 4 * SZ_X + 4 * SZ_W);
  u16* Ob  = Vb;   // V dead after transpose; reuse for attention output

  k_f2bf5<<<dim3(1024, 5), 256, 0, stream>>>(x, Wq, Wk, Wv, Wo,
                                             xb, wqb, wkb, wvb, wob,
                                             8388608 / 4, 4194304 / 4);

  // fused QKV: M=4096 x N=6144 x K=2048; 32x48 = 1536 blocks, ~4 blocks/CU resident
  k_gemm12<0><<<1536, 256, 0, stream>>>(xb, wqb, bq, bk, bv, Qb, Kb, Vb, nullptr, 32);

  k_transpose_v<<<dim3(32, 2, 32), 256, 0, stream>>>(Vb, Vtb);

  k_flash_attn<<<1024, 256, 0, stream>>>(Qb, Kb, Vtb, Ob);

  // output projection (fp32 out): 32x16 = 512 blocks
  k_gemm12<1><<<512, 256, 0, stream>>>(Ob, wob, bo, bo, bo, nullptr, nullptr, nullptr, out, 32);
}

// Round 18
// 260.399 us; speedup vs baseline: 1.0935x; 1.0935x over previous
//
#include <hip/hip_runtime.h>

typedef unsigned short u16;
typedef __attribute__((ext_vector_type(8))) short bf16x8;
typedef __attribute__((ext_vector_type(4))) float f32x4;
typedef __attribute__((ext_vector_type(4))) unsigned short u16x4;

__device__ __forceinline__ u16 f2bf(float f) {
  union { float f; unsigned u; } v; v.f = f;
  return (u16)((v.u + 0x7FFFu + ((v.u >> 16) & 1u)) >> 16);
}

__device__ __forceinline__ void gload16(const u16* g, u16* l) {
  __builtin_amdgcn_global_load_lds((const __attribute__((address_space(1))) void*)g,
                                   (__attribute__((address_space(3))) void*)l, 16, 0, 0);
}

// ---------------- fp32 -> bf16 convert (5 tensors fused) ----------------
__global__ __launch_bounds__(256) void k_f2bf5(
    const float* __restrict__ i0, const float* __restrict__ i1, const float* __restrict__ i2,
    const float* __restrict__ i3, const float* __restrict__ i4,
    u16* o0, u16* o1, u16* o2, u16* o3, u16* o4, int n4x, int n4w) {
  const int seg = blockIdx.y;
  const float* in = (seg == 0) ? i0 : (seg == 1) ? i1 : (seg == 2) ? i2 : (seg == 3) ? i3 : i4;
  u16* out = (seg == 0) ? o0 : (seg == 1) ? o1 : (seg == 2) ? o2 : (seg == 3) ? o3 : o4;
  const int n4 = (seg == 0) ? n4x : n4w;
  int i = blockIdx.x * 256 + threadIdx.x;
  const int stride = gridDim.x * 256;
  for (; i < n4; i += stride) {
    const float4 v = ((const float4*)in)[i];
    u16x4 o;
    o.x = f2bf(v.x); o.y = f2bf(v.y); o.z = f2bf(v.z); o.w = f2bf(v.w);
    ((u16x4*)out)[i] = o;
  }
}

// ---------------- 128x128 GEMM, m97-structure + T2 swizzle + multi-block TLP ----------
template <int OUT_F32>
__global__ __launch_bounds__(256, 4) void k_gemm12(
    const u16* __restrict__ A, const u16* __restrict__ Bt,
    const float* __restrict__ b0, const float* __restrict__ b1, const float* __restrict__ b2,
    u16* __restrict__ C0, u16* __restrict__ C1, u16* __restrict__ C2,
    float* __restrict__ Cf, int NBM)
{
  __shared__ alignas(16) u16 As[8192];   // [128 rows][64 k], swizzled
  __shared__ alignas(16) u16 Bs[8192];

  const int tid = threadIdx.x;
  const int lane = tid & 63, wid = tid >> 6;
  const int fr = lane & 15, fg = lane >> 4;
  const int wr = wid >> 1, wc = wid & 1;

  const int nblk = gridDim.x;
  const int q = nblk >> 3, r = nblk & 7;
  const int xcd = blockIdx.x & 7, lid = blockIdx.x >> 3;
  const int wgid = (xcd < r ? xcd * (q + 1) : r * (q + 1) + (xcd - r) * q) + lid;
  const int mb = wgid % NBM, nb = wgid / NBM;
  const long row0 = (long)mb * 128;
  const long col0 = (long)nb * 128;

  int sRow[4], sCol[4];
#pragma unroll
  for (int i = 0; i < 4; ++i) {
    const int g = (wid * 4 + i) * 64 + lane;
    sRow[i] = g >> 3;
    sCol[i] = ((g & 7) ^ (sRow[i] & 7)) << 3;
  }

  const int sw = fr & 7;
  const int aBase = (wr * 64 + fr) * 64;
  const int bBase = (wc * 64 + fr) * 64;
  const int pc0 = (fg ^ sw) << 3;
  const int pc1 = ((4 + fg) ^ sw) << 3;

  f32x4 acc[4][4] = {};

#pragma unroll 1
  for (int t = 0; t < 32; ++t) {
    if (t) __syncthreads();
    const long k0 = (long)t << 6;
#pragma unroll
    for (int i = 0; i < 4; ++i) {
      gload16(A  + (row0 + sRow[i]) * 2048L + k0 + sCol[i], &As[(wid * 4 + i) * 512]);
      gload16(Bt + (col0 + sRow[i]) * 2048L + k0 + sCol[i], &Bs[(wid * 4 + i) * 512]);
    }
    __syncthreads();

#pragma unroll
    for (int kc = 0; kc < 2; ++kc) {
      const int pc = kc ? pc1 : pc0;
      bf16x8 a[4], b[4];
#pragma unroll
      for (int i = 0; i < 4; ++i) {
        a[i] = *(const bf16x8*)&As[aBase + i * 1024 + pc];
        b[i] = *(const bf16x8*)&Bs[bBase + i * 1024 + pc];
      }
#pragma unroll
      for (int i = 0; i < 4; ++i)
#pragma unroll
        for (int j = 0; j < 4; ++j)
          acc[i][j] = __builtin_amdgcn_mfma_f32_16x16x32_bf16(a[i], b[j], acc[i][j], 0, 0, 0);
    }
  }

  const int seg = (int)(col0 >> 11);
  const long colL = col0 & 2047;
  const float* bp = (seg == 0) ? b0 : (seg == 1) ? b1 : b2;
  u16* Cb = (seg == 0) ? C0 : (seg == 1) ? C1 : C2;
#pragma unroll
  for (int j = 0; j < 4; ++j) {
    const long cN = colL + wc * 64 + j * 16 + fr;
    const float bv = bp[cN];
#pragma unroll
    for (int i = 0; i < 4; ++i) {
      const long rM = row0 + wr * 64 + i * 16 + fg * 4;
#pragma unroll
      for (int reg = 0; reg < 4; ++reg) {
        const float v = acc[i][j][reg] + bv;
        if (OUT_F32) Cf[(rM + reg) * 2048 + cN] = v;
        else         Cb[(rM + reg) * 2048 + cN] = f2bf(v);
      }
    }
  }
}

// ---------------- V transpose: V[b][s][h*128+d] -> Vt[(b*16+h)*128+d][s] ----------------
__global__ __launch_bounds__(256) void k_transpose_v(const u16* __restrict__ V,
                                                     u16* __restrict__ Vt) {
  __shared__ u16 t[64][68];
  const int bh = blockIdx.z;
  const long s0 = (long)blockIdx.x * 64;
  const long d0 = (long)blockIdx.y * 64;
  const int tid = threadIdx.x;
  const long rowbase = (long)(bh >> 4) * 2048;
  const int hcol = (bh & 15) * 128;
#pragma unroll
  for (int i = 0; i < 4; ++i) {
    const int v = tid + i * 256;
    const int r = v >> 4, c4 = (v & 15) << 2;
    const u16x4 val = *(const u16x4*)&V[(rowbase + s0 + r) * 2048 + hcol + d0 + c4];
    *(u16x4*)&t[r][c4] = val;
  }
  __syncthreads();
#pragma unroll
  for (int i = 0; i < 4; ++i) {
    const int v = tid + i * 256;
    const int dr = v >> 4, s4 = (v & 15) << 2;
    u16x4 o;
    o.x = t[s4 + 0][dr]; o.y = t[s4 + 1][dr]; o.z = t[s4 + 2][dr]; o.w = t[s4 + 3][dr];
    *(u16x4*)&Vt[((long)bh * 128 + d0 + dr) * 2048 + s0 + s4] = o;
  }
}

// ---------------- causal flash attention: kv-split waves + dbuf + counted vmcnt ----
// (R16 kernel, verbatim — best measured configuration.)
// 512 blocks (16 bx-pairs x 32 bh), 256 thr, QBLK=64, pass pairing (bx, 31-bx) =
// uniform 33 steps, K/V dbuf + prefetch + vmcnt(8), 2 blocks/CU. Wave (kvh, qh)
// computes its 32-kv slice x 32 q-rows: kf/vf LDS traffic halved, each read feeds
// 2 MFMAs. Per-wave online softmax over its kv-half; one merge per pass (stats +
// O-scratch overlaid on the then-dead K/V buffers, stride 132, syncthreads-fenced).
// Swapped operands (lane owns q-row fr).
__global__ __launch_bounds__(256, 2) void k_flash_attn(
    const u16* __restrict__ Q, const u16* __restrict__ K, const u16* __restrict__ Vt,
    u16* __restrict__ O)
{
  // SMEM carve (u16 units): [0,16384) Kt dbuf; [16384,32768) Vtt dbuf;
  // [32768,37888) P [4][32][40]; [37888,38400) stats (2x128 f32).
  // Merge scratch f32[2][32][132] overlays [0,16896) (K/V dead there).
  __shared__ alignas(16) u16 SM[38400];
  u16* Kt  = SM;
  u16* Vtt = SM + 16384;
  u16* Pl  = SM + 32768;
  float* statsM = (float*)(SM + 37888);
  float* statsL = (float*)(SM + 38144);
  float* mergeO = (float*)SM;

  const int tid = threadIdx.x;
  const int lane = tid & 63, wid = tid >> 6;
  const int fr = lane & 15, fg = lane >> 4;
  const int kvh = wid >> 1, qh = wid & 1;

  const int L = blockIdx.x;
  const int bh = (L & 7) * 4 + ((L >> 3) & 3);
  const int bx = L >> 5;

  const long rowbase = (long)(bh >> 4) * 2048;
  const int hcol = (bh & 15) * 128;
  const u16* Kg = K + rowbase * 2048 + hcol;
  const u16* Vg = Vt + (long)bh * 128 * 2048;
  const float scale2 = 0.08838834764831845f * 1.44269504089f;  // 1/sqrt(128)*log2(e)

  int kR[4], kC[4], vR[4], vC[4];
#pragma unroll
  for (int i = 0; i < 4; ++i) {
    const int g = (wid * 4 + i) * 64 + lane;
    kR[i] = g >> 4;
    kC[i] = ((g & 15) ^ (kR[i] & 7)) << 3;
    vR[i] = g >> 3;
    vC[i] = ((g & 7) ^ (vR[i] & 7)) << 3;
  }

  const int sw = fr & 7;
  int kOff[2][4];
#pragma unroll
  for (int kvt = 0; kvt < 2; ++kvt)
#pragma unroll
    for (int c = 0; c < 4; ++c)
      kOff[kvt][c] = kvh * 4096 + kvt * 2048 + fr * 128 + (((c * 4 + fg) ^ sw) << 3);
  const int vB = fr * 64 + (((kvh * 4 + fg) ^ sw) << 3);
  const int pBase = wid * 1280;                    // P [32][40] per wave

  for (int pass = 0; pass < 2; ++pass) {
    const int qblk = pass ? (31 - bx) : bx;
    const int n = qblk + 1;
    const int qw = qblk * 64 + qh * 32;            // wave's first q row

    bf16x8 qf[2][4];
#pragma unroll
    for (int qs = 0; qs < 2; ++qs)
#pragma unroll
      for (int c = 0; c < 4; ++c)
        qf[qs][c] = *(const bf16x8*)&Q[(rowbase + qw + qs * 16 + fr) * 2048 + hcol + c * 32 + fg * 8];

    f32x4 oacc[2][8] = {};
    float m_run[2] = {-1e30f, -1e30f}, l_run[2] = {0.0f, 0.0f};

    // prologue: stage kv-tile 0 into buffer 0
#pragma unroll
    for (int i = 0; i < 4; ++i) {
      gload16(Kg + (long)kR[i] * 2048 + kC[i], &Kt[(wid * 4 + i) * 512]);
      gload16(Vg + (long)vR[i] * 2048 + vC[i], &Vtt[(wid * 4 + i) * 512]);
    }

    int cur = 0;
    for (int j = 0; j < n; ++j) {
      if (j + 1 < n) {
        const long kv = (long)(j + 1) * 64;
#pragma unroll
        for (int i = 0; i < 4; ++i) {
          gload16(Kg + (kv + kR[i]) * 2048 + kC[i], &Kt[(cur ^ 1) * 8192 + (wid * 4 + i) * 512]);
          gload16(Vg + (long)vR[i] * 2048 + kv + vC[i], &Vtt[(cur ^ 1) * 8192 + (wid * 4 + i) * 512]);
        }
        asm volatile("s_waitcnt vmcnt(8)" ::: "memory");   // tile j landed; j+1 in flight
      } else {
        asm volatile("s_waitcnt vmcnt(0)" ::: "memory");
      }
      __builtin_amdgcn_s_barrier();
      __builtin_amdgcn_sched_barrier(0);

      const int kvbase = j * 64 + kvh * 32;        // wave's kv-slice start
      const bool skip = (kvbase >= qw + 32);       // slice fully above diagonal
      if (!skip) {
        const bool needmask = (kvbase + 31 > qw);

        // ---- QK^T swapped: st[qs][kvt] = K-slice x Q -> D[kv local][q = fr] ----
        f32x4 st[2][2] = {};
        const u16* kt = &Kt[cur * 8192];
        __builtin_amdgcn_s_setprio(1);
#pragma unroll
        for (int kvt = 0; kvt < 2; ++kvt)
#pragma unroll
          for (int c = 0; c < 4; ++c) {
            const bf16x8 kf = *(const bf16x8*)&kt[kOff[kvt][c]];
            st[0][kvt] = __builtin_amdgcn_mfma_f32_16x16x32_bf16(kf, qf[0][c], st[0][kvt], 0, 0, 0);
            st[1][kvt] = __builtin_amdgcn_mfma_f32_16x16x32_bf16(kf, qf[1][c], st[1][kvt], 0, 0, 0);
          }
        __builtin_amdgcn_s_setprio(0);

        // ---- scale/mask + slice max (q lane-local) ----
        float pmax[2] = {-1e30f, -1e30f};
        if (needmask) {
#pragma unroll
          for (int qs = 0; qs < 2; ++qs) {
            const int qg = qw + qs * 16 + fr;
#pragma unroll
            for (int kvt = 0; kvt < 2; ++kvt)
#pragma unroll
              for (int r = 0; r < 4; ++r) {
                const int kg = kvbase + kvt * 16 + fg * 4 + r;
                const float v = (kg <= qg) ? st[qs][kvt][r] * scale2 : -1e30f;
                st[qs][kvt][r] = v;
                pmax[qs] = fmaxf(pmax[qs], v);
              }
          }
        } else {
#pragma unroll
          for (int qs = 0; qs < 2; ++qs)
#pragma unroll
            for (int kvt = 0; kvt < 2; ++kvt)
#pragma unroll
              for (int r = 0; r < 4; ++r) {
                const float v = st[qs][kvt][r] * scale2;
                st[qs][kvt][r] = v;
                pmax[qs] = fmaxf(pmax[qs], v);
              }
        }
#pragma unroll
        for (int qs = 0; qs < 2; ++qs) {
          pmax[qs] = fmaxf(pmax[qs], __shfl_xor(pmax[qs], 16));
          pmax[qs] = fmaxf(pmax[qs], __shfl_xor(pmax[qs], 32));
        }

        // ---- defer-max rescale (THR=8 log2 units) ----
        const int ok = (pmax[0] <= m_run[0] + 8.f) & (pmax[1] <= m_run[1] + 8.f);
        if (!__all(ok)) {
#pragma unroll
          for (int qs = 0; qs < 2; ++qs) {
            const float nm = fmaxf(m_run[qs], pmax[qs]);
            const float al = exp2f(m_run[qs] - nm);
            l_run[qs] *= al;
            m_run[qs] = nm;
#pragma unroll
            for (int dt = 0; dt < 8; ++dt)
#pragma unroll
              for (int r = 0; r < 4; ++r) oacc[qs][dt][r] *= al;
          }
        }

        // ---- P = exp2(s-m), slice sum ----
        float lsum[2] = {0.f, 0.f};
#pragma unroll
        for (int qs = 0; qs < 2; ++qs)
#pragma unroll
          for (int kvt = 0; kvt < 2; ++kvt)
#pragma unroll
            for (int r = 0; r < 4; ++r) {
              const float p = exp2f(st[qs][kvt][r] - m_run[qs]);
              st[qs][kvt][r] = p;
              lsum[qs] += p;
            }
#pragma unroll
        for (int qs = 0; qs < 2; ++qs) {
          lsum[qs] += __shfl_xor(lsum[qs], 16);
          lsum[qs] += __shfl_xor(lsum[qs], 32);
          l_run[qs] += lsum[qs];
        }

        // ---- P -> wave-private LDS: Pl[q 0..31][kv-local 0..31] ----
#pragma unroll
        for (int qs = 0; qs < 2; ++qs)
#pragma unroll
          for (int kvt = 0; kvt < 2; ++kvt)
#pragma unroll
            for (int r = 0; r < 4; ++r)
              Pl[pBase + (qs * 16 + fr) * 40 + kvt * 16 + fg * 4 + r] = f2bf(st[qs][kvt][r]);
        asm volatile("s_waitcnt lgkmcnt(0)" ::: "memory");
        __builtin_amdgcn_sched_barrier(0);

        // ---- O_partial += V-slice^T x P: each vf feeds 2 MFMAs ----
        const u16* vt = &Vtt[cur * 8192];
        const bf16x8 pf0 = *(const bf16x8*)&Pl[pBase + fr * 40 + fg * 8];
        const bf16x8 pf1 = *(const bf16x8*)&Pl[pBase + (16 + fr) * 40 + fg * 8];
        __builtin_amdgcn_s_setprio(1);
#pragma unroll
        for (int dt = 0; dt < 8; ++dt) {
          const bf16x8 vf = *(const bf16x8*)&vt[vB + dt * 1024];
          oacc[0][dt] = __builtin_amdgcn_mfma_f32_16x16x32_bf16(vf, pf0, oacc[0][dt], 0, 0, 0);
          oacc[1][dt] = __builtin_amdgcn_mfma_f32_16x16x32_bf16(vf, pf1, oacc[1][dt], 0, 0, 0);
        }
        __builtin_amdgcn_s_setprio(0);
      }

      asm volatile("" ::: "memory");
      __builtin_amdgcn_s_barrier();          // all waves done reading buf[cur]
      cur ^= 1;
    }

    // ---- kv-half merge (once per pass): partner = wid ^ 2 ----
    if (fg == 0) {
#pragma unroll
      for (int qs = 0; qs < 2; ++qs) {
        statsM[wid * 32 + qs * 16 + fr] = m_run[qs];
        statsL[wid * 32 + qs * 16 + fr] = l_run[qs];
      }
    }
    __syncthreads();
    const int pw = wid ^ 2;
    float aself[2], ltot[2];
#pragma unroll
    for (int qs = 0; qs < 2; ++qs) {
      const float mp = statsM[pw * 32 + qs * 16 + fr];
      const float lp = statsL[pw * 32 + qs * 16 + fr];
      const float m = fmaxf(m_run[qs], mp);
      aself[qs] = exp2f(m_run[qs] - m);
      const float ap = exp2f(mp - m);
      ltot[qs] = aself[qs] * l_run[qs] + ap * lp;
    }
    if (kvh == 1) {
#pragma unroll
      for (int qs = 0; qs < 2; ++qs)
#pragma unroll
        for (int dt = 0; dt < 8; ++dt)
#pragma unroll
          for (int r = 0; r < 4; ++r)
            mergeO[qh * 4224 + (qs * 16 + fr) * 132 + dt * 16 + fg * 4 + r] =
                aself[qs] * oacc[qs][dt][r];
    }
    __syncthreads();
    if (kvh == 0) {
#pragma unroll
      for (int qs = 0; qs < 2; ++qs) {
        const float inv = 1.0f / ltot[qs];
        const long orow = (rowbase + qw + qs * 16 + fr) * 2048 + hcol;
#pragma unroll
        for (int dt = 0; dt < 8; ++dt) {
          u16x4 o;
#pragma unroll
          for (int r = 0; r < 4; ++r)
            o[r] = f2bf((aself[qs] * oacc[qs][dt][r] +
                         mergeO[qh * 4224 + (qs * 16 + fr) * 132 + dt * 16 + fg * 4 + r]) * inv);
          *(u16x4*)&O[orow + dt * 16 + fg * 4] = o;
        }
      }
    }
    __syncthreads();   // merge scratch dead before next pass restages K/V
  }
}

extern "C" void kernel_launch(void* const* d_in, const int* in_sizes, int n_in,
                              void* d_out, int out_size, void* d_ws, size_t ws_size,
                              hipStream_t stream) {
  const float* x  = (const float*)d_in[0];
  const float* Wq = (const float*)d_in[1];
  const float* bq = (const float*)d_in[2];
  const float* Wk = (const float*)d_in[3];
  const float* bk = (const float*)d_in[4];
  const float* Wv = (const float*)d_in[5];
  const float* bv = (const float*)d_in[6];
  const float* Wo = (const float*)d_in[7];
  const float* bo = (const float*)d_in[8];
  float* out = (float*)d_out;

  char* ws = (char*)d_ws;
  const size_t SZ_X = 16777216;   // 8M bf16
  const size_t SZ_W = 8388608;    // 4M bf16
  u16* xb  = (u16*)(ws);
  u16* wqb = (u16*)(ws + SZ_X);                 // wq/wk/wv contiguous = [6144][2048]
  u16* wkb = (u16*)(ws + SZ_X + 1 * SZ_W);
  u16* wvb = (u16*)(ws + SZ_X + 2 * SZ_W);
  u16* wob = (u16*)(ws + SZ_X + 3 * SZ_W);
  u16* Qb  = (u16*)(ws + 1 * SZ_X + 4 * SZ_W);
  u16* Kb  = (u16*)(ws + 2 * SZ_X + 4 * SZ_W);
  u16* Vb  = (u16*)(ws + 3 * SZ_X + 4 * SZ_W);
  u16* Vtb = (u16*)(ws + 4 * SZ_X + 4 * SZ_W);
  u16* Ob  = Vb;   // V dead after transpose; reuse for attention output

  k_f2bf5<<<dim3(1024, 5), 256, 0, stream>>>(x, Wq, Wk, Wv, Wo,
                                             xb, wqb, wkb, wvb, wob,
                                             8388608 / 4, 4194304 / 4);

  // fused QKV: M=4096 x N=6144 x K=2048; 32x48 = 1536 blocks, ~4 blocks/CU resident
  k_gemm12<0><<<1536, 256, 0, stream>>>(xb, wqb, bq, bk, bv, Qb, Kb, Vb, nullptr, 32);

  k_transpose_v<<<dim3(32, 2, 32), 256, 0, stream>>>(Vb, Vtb);

  k_flash_attn<<<512, 256, 0, stream>>>(Qb, Kb, Vtb, Ob);

  // output projection (fp32 out): 32x16 = 512 blocks
  k_gemm12<1><<<512, 256, 0, stream>>>(Ob, wob, bo, bo, bo, nullptr, nullptr, nullptr, out, 32);
}

// Round 19
// 253.555 us; speedup vs baseline: 1.1230x; 1.0270x over previous
//
#include <hip/hip_runtime.h>

typedef unsigned short u16;
typedef __attribute__((ext_vector_type(8))) short bf16x8;
typedef __attribute__((ext_vector_type(4))) float f32x4;
typedef __attribute__((ext_vector_type(4))) unsigned short u16x4;

__device__ __forceinline__ u16 f2bf(float f) {
  union { float f; unsigned u; } v; v.f = f;
  return (u16)((v.u + 0x7FFFu + ((v.u >> 16) & 1u)) >> 16);
}

__device__ __forceinline__ void gload16(const u16* g, u16* l) {
  __builtin_amdgcn_global_load_lds((const __attribute__((address_space(1))) void*)g,
                                   (__attribute__((address_space(3))) void*)l, 16, 0, 0);
}

// ---------------- fp32 -> bf16 convert (5 tensors fused) ----------------
__global__ __launch_bounds__(256) void k_f2bf5(
    const float* __restrict__ i0, const float* __restrict__ i1, const float* __restrict__ i2,
    const float* __restrict__ i3, const float* __restrict__ i4,
    u16* o0, u16* o1, u16* o2, u16* o3, u16* o4, int n4x, int n4w) {
  const int seg = blockIdx.y;
  const float* in = (seg == 0) ? i0 : (seg == 1) ? i1 : (seg == 2) ? i2 : (seg == 3) ? i3 : i4;
  u16* out = (seg == 0) ? o0 : (seg == 1) ? o1 : (seg == 2) ? o2 : (seg == 3) ? o3 : o4;
  const int n4 = (seg == 0) ? n4x : n4w;
  int i = blockIdx.x * 256 + threadIdx.x;
  const int stride = gridDim.x * 256;
  for (; i < n4; i += stride) {
    const float4 v = ((const float4*)in)[i];
    u16x4 o;
    o.x = f2bf(v.x); o.y = f2bf(v.y); o.z = f2bf(v.z); o.w = f2bf(v.w);
    ((u16x4*)out)[i] = o;
  }
}

// ---------------- 128x128 GEMM, m97-structure + T2 swizzle + multi-block TLP ----------
// VTRANS: seg==2 (V of fused QKV) is written TRANSPOSED to Vt[(b*16+h)*128+d][s]
// via an LDS-transposed tile (pad 136 -> 16B-aligned rows, ~2-way read conflicts),
// so the standalone transpose kernel (and its launch gap) disappears.
template <int OUT_F32, int VTRANS>
__global__ __launch_bounds__(256, 4) void k_gemm12(
    const u16* __restrict__ A, const u16* __restrict__ Bt,
    const float* __restrict__ b0, const float* __restrict__ b1, const float* __restrict__ b2,
    u16* __restrict__ C0, u16* __restrict__ C1, u16* __restrict__ C2,
    u16* __restrict__ Vt, float* __restrict__ Cf, int NBM)
{
  __shared__ alignas(16) u16 SMEM[17408];   // As[8192] | Bs[8192] ; T[128][136] overlay
  u16* const As = SMEM;
  u16* const Bs = SMEM + 8192;

  const int tid = threadIdx.x;
  const int lane = tid & 63, wid = tid >> 6;
  const int fr = lane & 15, fg = lane >> 4;
  const int wr = wid >> 1, wc = wid & 1;

  const int nblk = gridDim.x;
  const int q = nblk >> 3, r = nblk & 7;
  const int xcd = blockIdx.x & 7, lid = blockIdx.x >> 3;
  const int wgid = (xcd < r ? xcd * (q + 1) : r * (q + 1) + (xcd - r) * q) + lid;
  const int mb = wgid % NBM, nb = wgid / NBM;
  const long row0 = (long)mb * 128;
  const long col0 = (long)nb * 128;

  int sRow[4], sCol[4];
#pragma unroll
  for (int i = 0; i < 4; ++i) {
    const int g = (wid * 4 + i) * 64 + lane;
    sRow[i] = g >> 3;
    sCol[i] = ((g & 7) ^ (sRow[i] & 7)) << 3;
  }

  const int sw = fr & 7;
  const int aBase = (wr * 64 + fr) * 64;
  const int bBase = (wc * 64 + fr) * 64;
  const int pc0 = (fg ^ sw) << 3;
  const int pc1 = ((4 + fg) ^ sw) << 3;

  f32x4 acc[4][4] = {};

#pragma unroll 1
  for (int t = 0; t < 32; ++t) {
    if (t) __syncthreads();
    const long k0 = (long)t << 6;
#pragma unroll
    for (int i = 0; i < 4; ++i) {
      gload16(A  + (row0 + sRow[i]) * 2048L + k0 + sCol[i], &As[(wid * 4 + i) * 512]);
      gload16(Bt + (col0 + sRow[i]) * 2048L + k0 + sCol[i], &Bs[(wid * 4 + i) * 512]);
    }
    __syncthreads();

#pragma unroll
    for (int kc = 0; kc < 2; ++kc) {
      const int pc = kc ? pc1 : pc0;
      bf16x8 a[4], b[4];
#pragma unroll
      for (int i = 0; i < 4; ++i) {
        a[i] = *(const bf16x8*)&As[aBase + i * 1024 + pc];
        b[i] = *(const bf16x8*)&Bs[bBase + i * 1024 + pc];
      }
#pragma unroll
      for (int i = 0; i < 4; ++i)
#pragma unroll
        for (int j = 0; j < 4; ++j)
          acc[i][j] = __builtin_amdgcn_mfma_f32_16x16x32_bf16(a[i], b[j], acc[i][j], 0, 0, 0);
    }
  }

  const int seg = (int)(col0 >> 11);
  const long colL = col0 & 2047;

  if (VTRANS && seg == 2) {
    // ---- V: transpose through LDS, write Vt[(b*16+h)*128+d][s] coalesced ----
    __syncthreads();                                // all waves done with As/Bs
#pragma unroll
    for (int j = 0; j < 4; ++j) {
      const int dl = wc * 64 + j * 16 + fr;         // local d (tile col)
      const float bv = b2[colL + dl];
#pragma unroll
      for (int i = 0; i < 4; ++i) {
        const int sl = wr * 64 + i * 16 + fg * 4;   // local s (tile row)
        u16x4 tv;
#pragma unroll
        for (int reg = 0; reg < 4; ++reg) tv[reg] = f2bf(acc[i][j][reg] + bv);
        *(u16x4*)&SMEM[dl * 136 + sl] = tv;         // T[d][s], stride 136
      }
    }
    __syncthreads();
#pragma unroll
    for (int it = 0; it < 8; ++it) {
      const int c2 = it * 256 + tid;                // 0..2047: 128 d x 16 chunks
      const int dl = c2 >> 4;
      const int sc = (c2 & 15) << 3;
      const long gc = colL + dl;                    // model column of V
      const long h = gc >> 7, d = gc & 127;
      const long srow = row0 + sc;                  // row0 multiple of 128: same b
      const long b = srow >> 11, s = srow & 2047;
      const bf16x8 v = *(const bf16x8*)&SMEM[dl * 136 + sc];
      *(bf16x8*)&Vt[((b * 16 + h) * 128 + d) * 2048 + s] = v;
    }
    return;
  }

  const float* bp = (seg == 0) ? b0 : (seg == 1) ? b1 : b2;
  u16* Cb = (seg == 0) ? C0 : (seg == 1) ? C1 : C2;
#pragma unroll
  for (int j = 0; j < 4; ++j) {
    const long cN = colL + wc * 64 + j * 16 + fr;
    const float bv = bp[cN];
#pragma unroll
    for (int i = 0; i < 4; ++i) {
      const long rM = row0 + wr * 64 + i * 16 + fg * 4;
#pragma unroll
      for (int reg = 0; reg < 4; ++reg) {
        const float v = acc[i][j][reg] + bv;
        if (OUT_F32) Cf[(rM + reg) * 2048 + cN] = v;
        else         Cb[(rM + reg) * 2048 + cN] = f2bf(v);
      }
    }
  }
}

// ---------------- causal flash attention: kv-split waves + dbuf + counted vmcnt ----
// (R16 kernel, verbatim — best measured configuration.)
__global__ __launch_bounds__(256, 2) void k_flash_attn(
    const u16* __restrict__ Q, const u16* __restrict__ K, const u16* __restrict__ Vt,
    u16* __restrict__ O)
{
  __shared__ alignas(16) u16 SM[38400];
  u16* Kt  = SM;
  u16* Vtt = SM + 16384;
  u16* Pl  = SM + 32768;
  float* statsM = (float*)(SM + 37888);
  float* statsL = (float*)(SM + 38144);
  float* mergeO = (float*)SM;

  const int tid = threadIdx.x;
  const int lane = tid & 63, wid = tid >> 6;
  const int fr = lane & 15, fg = lane >> 4;
  const int kvh = wid >> 1, qh = wid & 1;

  const int L = blockIdx.x;
  const int bh = (L & 7) * 4 + ((L >> 3) & 3);
  const int bx = L >> 5;

  const long rowbase = (long)(bh >> 4) * 2048;
  const int hcol = (bh & 15) * 128;
  const u16* Kg = K + rowbase * 2048 + hcol;
  const u16* Vg = Vt + (long)bh * 128 * 2048;
  const float scale2 = 0.08838834764831845f * 1.44269504089f;  // 1/sqrt(128)*log2(e)

  int kR[4], kC[4], vR[4], vC[4];
#pragma unroll
  for (int i = 0; i < 4; ++i) {
    const int g = (wid * 4 + i) * 64 + lane;
    kR[i] = g >> 4;
    kC[i] = ((g & 15) ^ (kR[i] & 7)) << 3;
    vR[i] = g >> 3;
    vC[i] = ((g & 7) ^ (vR[i] & 7)) << 3;
  }

  const int sw = fr & 7;
  int kOff[2][4];
#pragma unroll
  for (int kvt = 0; kvt < 2; ++kvt)
#pragma unroll
    for (int c = 0; c < 4; ++c)
      kOff[kvt][c] = kvh * 4096 + kvt * 2048 + fr * 128 + (((c * 4 + fg) ^ sw) << 3);
  const int vB = fr * 64 + (((kvh * 4 + fg) ^ sw) << 3);
  const int pBase = wid * 1280;

  for (int pass = 0; pass < 2; ++pass) {
    const int qblk = pass ? (31 - bx) : bx;
    const int n = qblk + 1;
    const int qw = qblk * 64 + qh * 32;

    bf16x8 qf[2][4];
#pragma unroll
    for (int qs = 0; qs < 2; ++qs)
#pragma unroll
      for (int c = 0; c < 4; ++c)
        qf[qs][c] = *(const bf16x8*)&Q[(rowbase + qw + qs * 16 + fr) * 2048 + hcol + c * 32 + fg * 8];

    f32x4 oacc[2][8] = {};
    float m_run[2] = {-1e30f, -1e30f}, l_run[2] = {0.0f, 0.0f};

#pragma unroll
    for (int i = 0; i < 4; ++i) {
      gload16(Kg + (long)kR[i] * 2048 + kC[i], &Kt[(wid * 4 + i) * 512]);
      gload16(Vg + (long)vR[i] * 2048 + vC[i], &Vtt[(wid * 4 + i) * 512]);
    }

    int cur = 0;
    for (int j = 0; j < n; ++j) {
      if (j + 1 < n) {
        const long kv = (long)(j + 1) * 64;
#pragma unroll
        for (int i = 0; i < 4; ++i) {
          gload16(Kg + (kv + kR[i]) * 2048 + kC[i], &Kt[(cur ^ 1) * 8192 + (wid * 4 + i) * 512]);
          gload16(Vg + (long)vR[i] * 2048 + kv + vC[i], &Vtt[(cur ^ 1) * 8192 + (wid * 4 + i) * 512]);
        }
        asm volatile("s_waitcnt vmcnt(8)" ::: "memory");
      } else {
        asm volatile("s_waitcnt vmcnt(0)" ::: "memory");
      }
      __builtin_amdgcn_s_barrier();
      __builtin_amdgcn_sched_barrier(0);

      const int kvbase = j * 64 + kvh * 32;
      const bool skip = (kvbase >= qw + 32);
      if (!skip) {
        const bool needmask = (kvbase + 31 > qw);

        f32x4 st[2][2] = {};
        const u16* kt = &Kt[cur * 8192];
        __builtin_amdgcn_s_setprio(1);
#pragma unroll
        for (int kvt = 0; kvt < 2; ++kvt)
#pragma unroll
          for (int c = 0; c < 4; ++c) {
            const bf16x8 kf = *(const bf16x8*)&kt[kOff[kvt][c]];
            st[0][kvt] = __builtin_amdgcn_mfma_f32_16x16x32_bf16(kf, qf[0][c], st[0][kvt], 0, 0, 0);
            st[1][kvt] = __builtin_amdgcn_mfma_f32_16x16x32_bf16(kf, qf[1][c], st[1][kvt], 0, 0, 0);
          }
        __builtin_amdgcn_s_setprio(0);

        float pmax[2] = {-1e30f, -1e30f};
        if (needmask) {
#pragma unroll
          for (int qs = 0; qs < 2; ++qs) {
            const int qg = qw + qs * 16 + fr;
#pragma unroll
            for (int kvt = 0; kvt < 2; ++kvt)
#pragma unroll
              for (int r = 0; r < 4; ++r) {
                const int kg = kvbase + kvt * 16 + fg * 4 + r;
                const float v = (kg <= qg) ? st[qs][kvt][r] * scale2 : -1e30f;
                st[qs][kvt][r] = v;
                pmax[qs] = fmaxf(pmax[qs], v);
              }
          }
        } else {
#pragma unroll
          for (int qs = 0; qs < 2; ++qs)
#pragma unroll
            for (int kvt = 0; kvt < 2; ++kvt)
#pragma unroll
              for (int r = 0; r < 4; ++r) {
                const float v = st[qs][kvt][r] * scale2;
                st[qs][kvt][r] = v;
                pmax[qs] = fmaxf(pmax[qs], v);
              }
        }
#pragma unroll
        for (int qs = 0; qs < 2; ++qs) {
          pmax[qs] = fmaxf(pmax[qs], __shfl_xor(pmax[qs], 16));
          pmax[qs] = fmaxf(pmax[qs], __shfl_xor(pmax[qs], 32));
        }

        const int ok = (pmax[0] <= m_run[0] + 8.f) & (pmax[1] <= m_run[1] + 8.f);
        if (!__all(ok)) {
#pragma unroll
          for (int qs = 0; qs < 2; ++qs) {
            const float nm = fmaxf(m_run[qs], pmax[qs]);
            const float al = exp2f(m_run[qs] - nm);
            l_run[qs] *= al;
            m_run[qs] = nm;
#pragma unroll
            for (int dt = 0; dt < 8; ++dt)
#pragma unroll
              for (int r = 0; r < 4; ++r) oacc[qs][dt][r] *= al;
          }
        }

        float lsum[2] = {0.f, 0.f};
#pragma unroll
        for (int qs = 0; qs < 2; ++qs)
#pragma unroll
          for (int kvt = 0; kvt < 2; ++kvt)
#pragma unroll
            for (int r = 0; r < 4; ++r) {
              const float p = exp2f(st[qs][kvt][r] - m_run[qs]);
              st[qs][kvt][r] = p;
              lsum[qs] += p;
            }
#pragma unroll
        for (int qs = 0; qs < 2; ++qs) {
          lsum[qs] += __shfl_xor(lsum[qs], 16);
          lsum[qs] += __shfl_xor(lsum[qs], 32);
          l_run[qs] += lsum[qs];
        }

#pragma unroll
        for (int qs = 0; qs < 2; ++qs)
#pragma unroll
          for (int kvt = 0; kvt < 2; ++kvt)
#pragma unroll
            for (int r = 0; r < 4; ++r)
              Pl[pBase + (qs * 16 + fr) * 40 + kvt * 16 + fg * 4 + r] = f2bf(st[qs][kvt][r]);
        asm volatile("s_waitcnt lgkmcnt(0)" ::: "memory");
        __builtin_amdgcn_sched_barrier(0);

        const u16* vt = &Vtt[cur * 8192];
        const bf16x8 pf0 = *(const bf16x8*)&Pl[pBase + fr * 40 + fg * 8];
        const bf16x8 pf1 = *(const bf16x8*)&Pl[pBase + (16 + fr) * 40 + fg * 8];
        __builtin_amdgcn_s_setprio(1);
#pragma unroll
        for (int dt = 0; dt < 8; ++dt) {
          const bf16x8 vf = *(const bf16x8*)&vt[vB + dt * 1024];
          oacc[0][dt] = __builtin_amdgcn_mfma_f32_16x16x32_bf16(vf, pf0, oacc[0][dt], 0, 0, 0);
          oacc[1][dt] = __builtin_amdgcn_mfma_f32_16x16x32_bf16(vf, pf1, oacc[1][dt], 0, 0, 0);
        }
        __builtin_amdgcn_s_setprio(0);
      }

      asm volatile("" ::: "memory");
      __builtin_amdgcn_s_barrier();
      cur ^= 1;
    }

    if (fg == 0) {
#pragma unroll
      for (int qs = 0; qs < 2; ++qs) {
        statsM[wid * 32 + qs * 16 + fr] = m_run[qs];
        statsL[wid * 32 + qs * 16 + fr] = l_run[qs];
      }
    }
    __syncthreads();
    const int pw = wid ^ 2;
    float aself[2], ltot[2];
#pragma unroll
    for (int qs = 0; qs < 2; ++qs) {
      const float mp = statsM[pw * 32 + qs * 16 + fr];
      const float lp = statsL[pw * 32 + qs * 16 + fr];
      const float m = fmaxf(m_run[qs], mp);
      aself[qs] = exp2f(m_run[qs] - m);
      const float ap = exp2f(mp - m);
      ltot[qs] = aself[qs] * l_run[qs] + ap * lp;
    }
    if (kvh == 1) {
#pragma unroll
      for (int qs = 0; qs < 2; ++qs)
#pragma unroll
        for (int dt = 0; dt < 8; ++dt)
#pragma unroll
          for (int r = 0; r < 4; ++r)
            mergeO[qh * 4224 + (qs * 16 + fr) * 132 + dt * 16 + fg * 4 + r] =
                aself[qs] * oacc[qs][dt][r];
    }
    __syncthreads();
    if (kvh == 0) {
#pragma unroll
      for (int qs = 0; qs < 2; ++qs) {
        const float inv = 1.0f / ltot[qs];
        const long orow = (rowbase + qw + qs * 16 + fr) * 2048 + hcol;
#pragma unroll
        for (int dt = 0; dt < 8; ++dt) {
          u16x4 o;
#pragma unroll
          for (int r = 0; r < 4; ++r)
            o[r] = f2bf((aself[qs] * oacc[qs][dt][r] +
                         mergeO[qh * 4224 + (qs * 16 + fr) * 132 + dt * 16 + fg * 4 + r]) * inv);
          *(u16x4*)&O[orow + dt * 16 + fg * 4] = o;
        }
      }
    }
    __syncthreads();
  }
}

extern "C" void kernel_launch(void* const* d_in, const int* in_sizes, int n_in,
                              void* d_out, int out_size, void* d_ws, size_t ws_size,
                              hipStream_t stream) {
  const float* x  = (const float*)d_in[0];
  const float* Wq = (const float*)d_in[1];
  const float* bq = (const float*)d_in[2];
  const float* Wk = (const float*)d_in[3];
  const float* bk = (const float*)d_in[4];
  const float* Wv = (const float*)d_in[5];
  const float* bv = (const float*)d_in[6];
  const float* Wo = (const float*)d_in[7];
  const float* bo = (const float*)d_in[8];
  float* out = (float*)d_out;

  char* ws = (char*)d_ws;
  const size_t SZ_X = 16777216;   // 8M bf16
  const size_t SZ_W = 8388608;    // 4M bf16
  u16* xb  = (u16*)(ws);
  u16* wqb = (u16*)(ws + SZ_X);                 // wq/wk/wv contiguous = [6144][2048]
  u16* wkb = (u16*)(ws + SZ_X + 1 * SZ_W);
  u16* wvb = (u16*)(ws + SZ_X + 2 * SZ_W);
  u16* wob = (u16*)(ws + SZ_X + 3 * SZ_W);
  u16* Qb  = (u16*)(ws + 1 * SZ_X + 4 * SZ_W);
  u16* Kb  = (u16*)(ws + 2 * SZ_X + 4 * SZ_W);
  u16* Vb  = (u16*)(ws + 3 * SZ_X + 4 * SZ_W);
  u16* Vtb = (u16*)(ws + 4 * SZ_X + 4 * SZ_W);
  u16* Ob  = Vb;   // V buffer unused (V written transposed in-GEMM); reuse for attn O

  k_f2bf5<<<dim3(1024, 5), 256, 0, stream>>>(x, Wq, Wk, Wv, Wo,
                                             xb, wqb, wkb, wvb, wob,
                                             8388608 / 4, 4194304 / 4);

  // fused QKV: M=4096 x N=6144 x K=2048; V segment written transposed to Vtb
  k_gemm12<0, 1><<<1536, 256, 0, stream>>>(xb, wqb, bq, bk, bv,
                                           Qb, Kb, nullptr, Vtb, nullptr, 32);

  k_flash_attn<<<512, 256, 0, stream>>>(Qb, Kb, Vtb, Ob);

  // output projection (fp32 out): 32x16 = 512 blocks
  k_gemm12<1, 0><<<512, 256, 0, stream>>>(Ob, wob, bo, bo, bo,
                                          nullptr, nullptr, nullptr, nullptr, out, 32);
}